// Round 3
// baseline (556.094 us; speedup 1.0000x reference)
//
#include <hip/hip_runtime.h>

typedef __attribute__((ext_vector_type(8))) short short8;
typedef __attribute__((ext_vector_type(4))) float floatx4;

#define QK_LD 136   // shorts; rows 16B-aligned (136*2=272, mult of 16)
#define VT_LD 72

// round-to-nearest-even bf16 sits in bits [31:16] of the result
__device__ __forceinline__ unsigned int rne_hi(float f) {
  union { float f; unsigned int u; } v; v.f = f;
  return v.u + 0x7fffu + ((v.u >> 16) & 1u);
}
// pack bf16(f0) -> low16, bf16(f1) -> high16 (one v_perm_b32)
__device__ __forceinline__ unsigned int pack_bf2(float f0, float f1) {
  return __builtin_amdgcn_perm(rne_hi(f1), rne_hi(f0), 0x07060302u);
}
__device__ __forceinline__ unsigned short f2bf(float f) {
  return (unsigned short)(rne_hi(f) >> 16);
}

__launch_bounds__(256, 4)
__global__ void attn_fwd(const float* __restrict__ qkv,
                         const int* __restrict__ kvlen_p,
                         float* __restrict__ out) {
  // Ks 64*136*2 = 17408 B, Vts 128*72*2 = 18432 B -> 35840 B -> 4 blocks/CU
  __shared__ unsigned short Ks[64 * QK_LD];   // K (bf16); rows 16w..16w+15 reused as P
  __shared__ unsigned short Vts[128 * VT_LD]; // V^T [d][s], swizzled cols

  const int bid  = blockIdx.x;
  const int h    = bid & 31;
  const int b    = bid >> 5;
  const int tid  = threadIdx.x;
  const int lane = tid & 63;
  const int w    = tid >> 6;        // wave: query rows 16w..16w+15
  const int l15  = lane & 15;
  const int quad = lane >> 4;
  const int kvlen = kvlen_p[0];

  const float4* g4 = (const float4*)qkv;  // row = 96 float4 (Q|K|V = 32|32|32)

  // ---- Q A-fragments: global -> registers (wave-private, skips LDS) ----
  // lane (l15, quad) needs Q[row=16w+l15][k=32ks+8quad .. +7]
  const float4* qg = g4 + ((size_t)((b * 64 + 16 * w + l15) * 32 + h)) * 96 + 2 * quad;
  float4 qf32[8];
  #pragma unroll
  for (int ks = 0; ks < 4; ++ks) {
    qf32[2 * ks]     = qg[8 * ks];
    qf32[2 * ks + 1] = qg[8 * ks + 1];
  }

  // ---- stage K, V: global fp32 -> LDS bf16 ----
  #pragma unroll 2
  for (int it = 0; it < 8; ++it) {
    int i  = tid + 256 * it;          // 64 rows x 32 float4-chunks
    int s  = i >> 5;
    int c4 = i & 31;
    const float4* rp = g4 + ((size_t)((b * 64 + s) * 32 + h)) * 96;

    float4 dk = rp[32 + c4];
    uint2 pk = { pack_bf2(dk.x, dk.y), pack_bf2(dk.z, dk.w) };
    *(uint2*)&Ks[s * QK_LD + c4 * 4] = pk;

    float4 dv = rp[64 + c4];
    // transpose-scatter V -> Vt[d][s]; col swizzle keeps stores ~2-way (free)
    int col = (s + 8 * ((c4 >> 1) & 7)) & 63;   // (d>>3)&7 == (c4>>1)&7 for these 4 d
    unsigned short* vp = &Vts[(c4 * 4) * VT_LD + col];
    vp[0 * VT_LD] = f2bf(dv.x);
    vp[1 * VT_LD] = f2bf(dv.y);
    vp[2 * VT_LD] = f2bf(dv.z);
    vp[3 * VT_LD] = f2bf(dv.w);
  }

  // convert Q (loads have long since landed under the staging loop)
  short8 qfrag[4];
  #pragma unroll
  for (int ks = 0; ks < 4; ++ks) {
    union { unsigned int u[4]; short8 s8; } cv;
    float4 a0 = qf32[2 * ks], a1 = qf32[2 * ks + 1];
    cv.u[0] = pack_bf2(a0.x, a0.y);
    cv.u[1] = pack_bf2(a0.z, a0.w);
    cv.u[2] = pack_bf2(a1.x, a1.y);
    cv.u[3] = pack_bf2(a1.z, a1.w);
    qfrag[ks] = cv.s8;
  }
  __syncthreads();

  // ---- scores: S = Q K^T * scale ----
  const float scale = 0.08838834764831845f;  // 1/sqrt(128)
  floatx4 zero4 = {0.f, 0.f, 0.f, 0.f};
  floatx4 accS[4] = {zero4, zero4, zero4, zero4};
  #pragma unroll
  for (int ks = 0; ks < 4; ++ks) {
    #pragma unroll
    for (int nt = 0; nt < 4; ++nt) {
      short8 bf = *(const short8*)&Ks[(16 * nt + l15) * QK_LD + 32 * ks + 8 * quad];
      accS[nt] = __builtin_amdgcn_mfma_f32_16x16x32_bf16(qfrag[ks], bf, accS[nt], 0, 0, 0);
    }
  }
  __syncthreads();  // all waves done reading Ks -> rows reusable as P scratch

  // ---- softmax (C-layout: row = 4*quad + r, col = 16*nt + l15) ----
  float sv[4][4];
  #pragma unroll
  for (int nt = 0; nt < 4; ++nt) {
    bool masked = (16 * nt + l15) >= kvlen;
    #pragma unroll
    for (int r = 0; r < 4; ++r)
      sv[nt][r] = masked ? -__builtin_inff() : accS[nt][r] * scale;
  }
  float rowmax[4], rsum[4], rcpl[4];
  #pragma unroll
  for (int r = 0; r < 4; ++r)
    rowmax[r] = fmaxf(fmaxf(sv[0][r], sv[1][r]), fmaxf(sv[2][r], sv[3][r]));
  #pragma unroll
  for (int m = 1; m <= 8; m <<= 1)
    #pragma unroll
    for (int r = 0; r < 4; ++r)
      rowmax[r] = fmaxf(rowmax[r], __shfl_xor(rowmax[r], m));

  // P (bf16) into this wave's own Ks rows — wave-local, in-order DS, no barrier
  unsigned short* Pbase = &Ks[16 * w * QK_LD];
  #pragma unroll
  for (int r = 0; r < 4; ++r) rsum[r] = 0.f;
  #pragma unroll
  for (int nt = 0; nt < 4; ++nt)
    #pragma unroll
    for (int r = 0; r < 4; ++r) {
      float e = __expf(sv[nt][r] - rowmax[r]);
      rsum[r] += e;
      Pbase[(4 * quad + r) * QK_LD + 16 * nt + l15] = f2bf(e);
    }
  #pragma unroll
  for (int m = 1; m <= 8; m <<= 1)
    #pragma unroll
    for (int r = 0; r < 4; ++r)
      rsum[r] += __shfl_xor(rsum[r], m);
  #pragma unroll
  for (int r = 0; r < 4; ++r) rcpl[r] = 1.0f / rsum[r];

  // ---- O = P V ----
  const int arow = (16 * w + l15) * QK_LD + 8 * quad;  // P A-frag base (in Ks region)
  floatx4 accO[8] = {zero4, zero4, zero4, zero4, zero4, zero4, zero4, zero4};
  #pragma unroll
  for (int ks = 0; ks < 2; ++ks) {
    short8 a = *(const short8*)&Ks[arow + 32 * ks];
    #pragma unroll
    for (int nt = 0; nt < 8; ++nt) {
      int vrow = 16 * nt + l15;                      // d
      int vcol = ((32 * ks + 8 * quad) + 8 * ((vrow >> 3) & 7)) & 63;  // swizzle-aware
      short8 bf = *(const short8*)&Vts[vrow * VT_LD + vcol];
      accO[nt] = __builtin_amdgcn_mfma_f32_16x16x32_bf16(a, bf, accO[nt], 0, 0, 0);
    }
  }

  // ---- epilogue: scale by 1/l, fp32 stores; nt inner so 128B lines complete fast ----
  #pragma unroll
  for (int r = 0; r < 4; ++r) {
    const int obase = ((b * 64 + 16 * w + 4 * quad + r) * 32 + h) * 128 + l15;
    #pragma unroll
    for (int nt = 0; nt < 8; ++nt)
      out[obase + nt * 16] = accO[nt][r] * rcpl[r];
  }
}

extern "C" void kernel_launch(void* const* d_in, const int* in_sizes, int n_in,
                              void* d_out, int out_size, void* d_ws, size_t ws_size,
                              hipStream_t stream) {
  const float* qkv = (const float*)d_in[0];
  const int* kvlen = (const int*)d_in[1];
  float* out       = (float*)d_out;
  attn_fwd<<<dim3(128 * 32), dim3(256), 0, stream>>>(qkv, kvlen, out);
}